// Round 10
// baseline (230.140 us; speedup 1.0000x reference)
//
#include <hip/hip_runtime.h>
#include <hip/hip_bf16.h>

using uint32   = unsigned int;
using ushort_t = unsigned short;
using short8   = __attribute__((ext_vector_type(8))) short;
using uint4v   = __attribute__((ext_vector_type(4))) uint32;
using float4v  = __attribute__((ext_vector_type(4))) float;
using floatx16 = __attribute__((ext_vector_type(16))) float;

#define M_DIM 32
#define K_DIM 8192
#define N_DIM 28672
#define QROW  (N_DIM/8)   /* 3584 dwords per qweight k-row */
#define KSPLIT 8
#define BN    128
#define NB    (N_DIM/BN)  /* 224 n-blocks */
#define CH    128         /* k per chunk == QGS */
#define NCH   8           /* chunks per block (K_DIM / KSPLIT / CH) */

typedef __attribute__((address_space(3))) uint32 lds_u32;
typedef const __attribute__((address_space(1))) uint32 glb_u32;

__device__ ushort_t g_xr2[M_DIM * K_DIM]; // rotated x, k-octet-major MFMA-A order
__device__ float    g_S[64 * M_DIM];      // per-group row sums of bf16(xr)

__device__ __forceinline__ float bf2f(ushort_t u){
  unsigned int v = ((unsigned int)u) << 16;
  return __builtin_bit_cast(float, v);
}
__device__ __forceinline__ ushort_t f2bf(float f){
  return __builtin_bit_cast(ushort_t, __float2bfloat16(f)); // RNE
}

// ------------- prep: rotation + group sums, and bias broadcast ---------
__global__ __launch_bounds__(256) void prep_kernel(
    const float* __restrict__ x, const float* __restrict__ theta,
    const int* __restrict__ pairs, const float* __restrict__ cs,
    const float* __restrict__ bias, float* __restrict__ out)
{
  if (blockIdx.x >= 512){
    const int b  = blockIdx.x - 512;
    const int n  = (b % (N_DIM/256))*256 + threadIdx.x;
    const int m0 = (b / (N_DIM/256))*8;
    const float bv = bias[n];
    #pragma unroll
    for (int m = 0; m < 8; ++m) out[(size_t)(m0+m)*N_DIM + n] = bv;
    return;
  }
  __shared__ float xb[4][128];
  const int u    = threadIdx.x >> 6;
  const int lane = threadIdx.x & 63;
  const int id   = blockIdx.x * 4 + u;   // 0..2047 = m*64+g
  const int m    = id >> 6;
  const int g    = id & 63;
  const float* xp = x + m*K_DIM + g*128;
  int   ip[8], jp[8];
  float cv[8], sv[8];
  #pragma unroll
  for (int k = 0; k < 8; ++k){
    ip[k] = pairs[k*128 + 2*lane];
    jp[k] = pairs[k*128 + 2*lane + 1];
    const float th = theta[k*(K_DIM/2) + g*64 + lane];
    cv[k] = cosf(th); sv[k] = sinf(th);
  }
  xb[u][lane]    = xp[lane];
  xb[u][lane+64] = xp[lane+64];
  #pragma unroll
  for (int k = 0; k < 8; ++k){
    __syncthreads();
    const float xi = xb[u][ip[k]], xj = xb[u][jp[k]];
    xb[u][ip[k]] = cv[k]*xi - sv[k]*xj;
    xb[u][jp[k]] = sv[k]*xi + cv[k]*xj;
  }
  __syncthreads();
  const int base = g*128;
  const int k0 = base + lane, k1 = base + lane + 64;
  const ushort_t b0 = f2bf(xb[u][lane]    * cs[k0]);
  const ushort_t b1 = f2bf(xb[u][lane+64] * cs[k1]);
  g_xr2[(((size_t)(k0>>3))*32 + m)*8 + (k0&7)] = b0;
  g_xr2[(((size_t)(k1>>3))*32 + m)*8 + (k1&7)] = b1;
  float sum = bf2f(b0) + bf2f(b1);
  #pragma unroll
  for (int d = 32; d > 0; d >>= 1) sum += __shfl_xor(sum, d, 64);
  if (lane == 0) g_S[g*M_DIM + m] = sum;
}

// ---- GEMM: pinned global_load_lds B staging, row-major LDS, 3-buf ----
// B never touches VGPRs: 2 x global_load_lds(16B) per thread per chunk,
// issued 2 chunks ahead (intrinsic = un-sinkable issue point). Counted
// vmcnt(2) at the end-of-chunk barrier leaves the newest stage in flight
// (T3+T4). LDS row-major [128 k][16 dwords]; reads are 8x b32 per kk at
// 64B stride -> compiler pairs ds_read2_b32; 4col x 2koct, 8-way
// broadcast, worst 2-way bank alias = free. No ds_writes at all.
__global__ __launch_bounds__(256, 4) void gemm_kernel(
    const uint32* __restrict__ qw, const uint32* __restrict__ qz,
    const float* __restrict__ scales, float* __restrict__ out)
{
  __shared__ uint32 T[3][CH*16];            // 3 x 8 KB B-chunk panels
  const int bid  = blockIdx.x;
  const int ks   = bid & (KSPLIT-1);
  const int nb   = bid >> 3;
  const int tid  = threadIdx.x;
  const int w    = tid >> 6;                // 0..3
  const int lane = tid & 63;
  const int l31  = lane & 31;
  const int koct = lane >> 5;
  const int n0   = nb * BN;
  const int n    = n0 + w*32 + l31;
  const uint32 sh = (uint32)((l31 & 7)*4);
  const int col  = w*4 + (l31 >> 3);        // panel dword-column 0..15
  const int k0   = ks * (NCH*CH);           // 1024*ks

  // staging geometry: pass q in {0,1}; thread covers 16B of the 8KB panel
  const int srow = tid >> 2;                // 0..63 (+ q*64)
  const int scq  = (tid & 3)*4;             // dword col of 16B unit
  const uint32* sbase = qw + (size_t)(k0 + srow)*QROW + (n0>>3) + scq;
  const ushort_t* abase = g_xr2 + (size_t)k0*32;

  auto stage = [&](int c, int b){
    #pragma unroll
    for (int q = 0; q < 2; ++q){
      const uint32* gp = sbase + (size_t)(c*CH + q*64)*QROW;
      lds_u32* lp = (lds_u32*)&T[b][q*1024 + w*256];  // wave-uniform; HW adds lane*16
      __builtin_amdgcn_global_load_lds((glb_u32*)gp, lp, 16, 0, 0);
    }
  };

  float accT[16];
  #pragma unroll
  for (int r = 0; r < 16; ++r) accT[r] = 0.f;

  // prelude: stage chunks 0,1
  stage(0, 0);
  stage(1, 1);
  asm volatile("s_waitcnt vmcnt(2)" ::: "memory");   // chunk 0 staged
  __builtin_amdgcn_s_barrier();
  asm volatile("" ::: "memory");

  #pragma unroll
  for (int c = 0; c < NCH; ++c){
    const int cb = c % 3;
    // ---- top: issue everything BEFORE the staging instrs, so no
    // compiler-inserted wait ever drains the staged loads ----
    const float  s  = scales[(size_t)(ks*NCH + c)*N_DIM + n];
    const uint32 zq = qz[(size_t)(ks*NCH + c)*QROW + (n>>3)];
    const float* Sg = &g_S[(size_t)(ks*NCH + c)*M_DIM];
    float4v Sv[4];
    #pragma unroll
    for (int q = 0; q < 4; ++q)
      Sv[q] = *(const float4v*)(Sg + q*8 + 4*koct);  // rows q*8+4*koct+0..3
    const ushort_t* ab = abase + (size_t)c*CH*32;
    short8 av[8];
    #pragma unroll
    for (int i = 0; i < 8; ++i)
      av[i] = *(const short8*)(ab + ((i*2 + koct)*32 + l31)*8);
    if (c + 2 < NCH) stage(c + 2, (c + 2) % 3);      // depth-2 prefetch

    floatx16 acc;
    #pragma unroll
    for (int r = 0; r < 16; ++r) acc[r] = 0.f;

    const uint32* Tc = &T[cb][0];
    #pragma unroll
    for (int kk = 0; kk < 8; ++kk){
      const int rb = kk*16 + koct*8;
      uint32 p[8];
      #pragma unroll
      for (int j = 0; j < 8; ++j) p[j] = Tc[(rb + j)*16 + col];
      // mask BEFORE merge (r5's merged form OR-corrupted nibbles)
      uint4v bp;
      bp.x = ((p[0] >> sh) & 15u) | (((p[1] >> sh) & 15u) << 16) | 0x43004300u;
      bp.y = ((p[2] >> sh) & 15u) | (((p[3] >> sh) & 15u) << 16) | 0x43004300u;
      bp.z = ((p[4] >> sh) & 15u) | (((p[5] >> sh) & 15u) << 16) | 0x43004300u;
      bp.w = ((p[6] >> sh) & 15u) | (((p[7] >> sh) & 15u) << 16) | 0x43004300u;
      acc = __builtin_amdgcn_mfma_f32_32x32x16_bf16(
                av[kk], __builtin_bit_cast(short8, bp), acc, 0, 0, 0);
    }
    // fold scale + this group's zero-point correction:
    //   accT += s*acc - s*(128+z)*S_g[row]
    const float t = s * (float)(128u + ((zq >> sh) & 15u));
    #pragma unroll
    for (int r = 0; r < 16; ++r){
      accT[r] = fmaf(s, acc[r], accT[r]);
      accT[r] = fmaf(-t, Sv[r >> 2][r & 3], accT[r]);
    }
    if (c + 1 < NCH){
      // counted barrier: wait stage(c+1) (leave stage(c+2) in flight),
      // drain LDS reads, then cross. WAR on buf (c+2)%3 is safe: its
      // readers (chunk c-1) passed the previous barrier with lgkm(0).
      asm volatile("s_waitcnt vmcnt(2)" ::: "memory");
      asm volatile("s_waitcnt lgkmcnt(0)" ::: "memory");
      __builtin_amdgcn_s_barrier();
      asm volatile("" ::: "memory");
    }
  }
  // C/D layout (HW-verified m74/m101): col=lane&31, row=(r&3)+8*(r>>2)+4*koct
  #pragma unroll
  for (int r = 0; r < 16; ++r){
    const int row = (r & 3) + 8*(r >> 2) + 4*koct;
    atomicAdd(out + (size_t)row*N_DIM + n, accT[r]);
  }
}

extern "C" void kernel_launch(void* const* d_in, const int* in_sizes, int n_in,
                              void* d_out, int out_size, void* d_ws, size_t ws_size,
                              hipStream_t stream)
{
  const float*  x      = (const float*)d_in[0];
  const uint32* qw     = (const uint32*)d_in[1];
  const uint32* qz     = (const uint32*)d_in[2];
  const float*  scales = (const float*)d_in[3];
  const float*  bias   = (const float*)d_in[4];
  const float*  theta  = (const float*)d_in[5];
  const int*    pairs  = (const int*)d_in[6];
  const float*  cs     = (const float*)d_in[7];
  float* out = (float*)d_out;

  prep_kernel<<<dim3(512 + (N_DIM/256)*4), dim3(256), 0, stream>>>(
      x, theta, pairs, cs, bias, out);
  gemm_kernel<<<dim3(NB*KSPLIT), dim3(256), 0, stream>>>(qw, qz, scales, out);
}